// Round 14
// baseline (313.376 us; speedup 1.0000x reference)
//
#include <hip/hip_runtime.h>

constexpr int F_IN  = 256;
constexpr int F_OUT = 128;

constexpr int NPSH  = 9;              // 512 nodes per super-bucket
constexpr int NPS   = 1 << NPSH;      // 512
constexpr int EPT   = 16;             // edges/thread in partition pass
constexpr int BATCH = 256 * EPT;      // 4096 edges per block batch
constexpr int CAPS  = 9216;           // slots per segment (avg 8192, +11 sigma)

typedef __attribute__((ext_vector_type(8))) short short8;
typedef __attribute__((ext_vector_type(4))) float f32x4;

// fp32 -> bf16 round-to-nearest-even
__device__ __forceinline__ unsigned short f2bf(float f) {
    unsigned u = __float_as_uint(f);
    u += 0x7fffu + ((u >> 16) & 1u);
    return (unsigned short)(u >> 16);
}

// ---------------------------------------------------------------------------
// Prep: Wt swizzled K-major. Seeds segmented append cursors cursorA[s]=s*CAPS.
// ---------------------------------------------------------------------------
__global__ void prep_wt_kernel(const float* __restrict__ W,
                               unsigned short* __restrict__ Wt,
                               int* __restrict__ cursorA)
{
    int n = blockIdx.x;      // 0..127
    int k = threadIdx.x;     // 0..255
    int ks = k >> 5, kk = k & 31;
    Wt[((ks * F_OUT) + n) * 32 + kk] = f2bf(W[k * F_OUT + n]);
    if (blockIdx.x == 0) cursorA[threadIdx.x] = threadIdx.x * CAPS;
}

// ---------------------------------------------------------------------------
// FUSED: gemm (blocks [0,ngemm)) + partition (blocks [ngemm, ngemm+npart)).
// (R13-proven: 311.6us total; disjoint data, no ordering constraint.)
// ---------------------------------------------------------------------------
#define BS_LD 40   // 32 + 8 pad shorts; 80B row stride, 16B aligned

__global__ __launch_bounds__(256) void fused_gemm_partition_kernel(
    const float* __restrict__ x, const unsigned short* __restrict__ Wt,
    unsigned short* __restrict__ h, int n_nodes, int ngemm,
    const int* __restrict__ src, const int* __restrict__ dst,
    const float* __restrict__ vals, int* __restrict__ cursorA,
    uint2* __restrict__ payA, int n_edges)
{
    __shared__ unsigned short Bs[F_OUT * BS_LD];   // 10240 B (gemm path)
    __shared__ int hist[256];                      // 1 KB (partition path)
    __shared__ int base[256];                      // 1 KB (partition path)

    const int tid = threadIdx.x;

    if ((int)blockIdx.x < ngemm) {
        // ----------------- gemm path -----------------
        const int wave = tid >> 6;
        const int lane = tid & 63;
        const int m16  = lane & 15;
        const int quad = lane >> 4;
        const int k0q  = quad * 8;
        const int arow = blockIdx.x * 64 + wave * 16 + m16;
        const bool inb = arow < n_nodes;

        f32x4 acc[8];
        #pragma unroll
        for (int t = 0; t < 8; ++t) acc[t] = (f32x4)(0.f);

        float4 a0 = make_float4(0.f,0.f,0.f,0.f), a1 = a0;
        if (inb) {
            a0 = *(const float4*)&x[(long long)arow * F_IN + k0q];
            a1 = *(const float4*)&x[(long long)arow * F_IN + k0q + 4];
        }

        for (int ks = 0; ks < 8; ++ks) {
            const uint4* wsrc = (const uint4*)(Wt + (size_t)ks * F_OUT * 32);
            #pragma unroll
            for (int p = 0; p < 2; ++p) {
                int c   = p * 256 + tid;
                int row = c >> 2;
                int o16 = c & 3;
                *(uint4*)&Bs[row * BS_LD + o16 * 8] = wsrc[c];
            }
            __syncthreads();

            short8 af;
            af[0] = (short)f2bf(a0.x); af[1] = (short)f2bf(a0.y);
            af[2] = (short)f2bf(a0.z); af[3] = (short)f2bf(a0.w);
            af[4] = (short)f2bf(a1.x); af[5] = (short)f2bf(a1.y);
            af[6] = (short)f2bf(a1.z); af[7] = (short)f2bf(a1.w);
            if (!inb) af = (short8)0;

            if (ks < 7 && inb) {
                int kn = (ks + 1) * 32 + k0q;
                a0 = *(const float4*)&x[(long long)arow * F_IN + kn];
                a1 = *(const float4*)&x[(long long)arow * F_IN + kn + 4];
            }

            #pragma unroll
            for (int t = 0; t < 8; ++t) {
                int n = t * 16 + m16;
                short8 bf = *(const short8*)&Bs[n * BS_LD + k0q];
                acc[t] = __builtin_amdgcn_mfma_f32_16x16x32_bf16(af, bf, acc[t], 0, 0, 0);
            }
            __syncthreads();
        }

        const int rbase = blockIdx.x * 64 + wave * 16 + quad * 4;
        #pragma unroll
        for (int r = 0; r < 4; ++r) {
            int grow = rbase + r;
            if (grow < n_nodes) {
                #pragma unroll
                for (int t = 0; t < 8; ++t)
                    h[(long long)grow * F_OUT + t * 16 + m16] = f2bf(acc[t][r]);
            }
        }
    } else {
        // ----------------- partition path -----------------
        const int i0 = (blockIdx.x - ngemm) * BATCH;

        hist[tid] = 0;
        __syncthreads();

        uint2 p[EPT];
        int   sb[EPT];
        int   rk[EPT];
        #pragma unroll
        for (int j = 0; j < EPT; ++j) {
            int i = i0 + j * 256 + tid;
            sb[j] = -1;
            if (i < n_edges) {
                int d = dst[i];
                p[j] = make_uint2((unsigned)src[i] | ((unsigned)(d & (NPS - 1)) << 17),
                                  __float_as_uint(vals[i]));
                sb[j] = d >> NPSH;
                rk[j] = atomicAdd(&hist[sb[j]], 1);
            }
        }
        __syncthreads();
        { int v = hist[tid]; if (v) base[tid] = atomicAdd(&cursorA[tid], v); }
        __syncthreads();
        #pragma unroll
        for (int j = 0; j < EPT; ++j)
            if (sb[j] >= 0) payA[base[sb[j]] + rk[j]] = p[j];
    }
}

// ---------------------------------------------------------------------------
// Sort within super-bucket — SINGLE-READ rewrite. One block per super
// (196 blocks, 512 threads, <1 block/CU so latency is unhidden — critical
// path matters). Each thread loads its <=16 edges into REGISTERS (static
// indexing only), histograms from registers, then scatters from registers:
// eliminates the second full 12.8MB payA read. 512-bin exclusive scan via
// wave shfl-scan (6 steps, no barriers) + serial 8-wave-base scan:
// 3 barriers in the scan instead of 18.
// ---------------------------------------------------------------------------
__global__ __launch_bounds__(512) void sort_super_kernel(
    const uint2* __restrict__ payA, const int* __restrict__ super_end,
    uint2* __restrict__ sorted, int* __restrict__ offsets, int n_nodes)
{
    __shared__ int bins[NPS];      // 2 KB
    __shared__ int bcur[NPS];      // 2 KB
    __shared__ int wsum[8];

    const int sp  = blockIdx.x;
    const int tid = threadIdx.x;
    const int lo  = sp * CAPS;
    const int hi  = super_end[sp];

    bins[tid] = 0;
    __syncthreads();

    // load <=16 edges/thread into registers + histogram (covers first 8192)
    uint2 r[16];
    int   nr = 0;
    #pragma unroll
    for (int j = 0; j < 16; ++j) {
        int e = lo + j * 512 + tid;
        if (e < hi) {
            r[j] = payA[e];
            atomicAdd(&bins[(r[j].x >> 17) & (NPS - 1)], 1);
            nr = j + 1;
        }
    }
    // statistical tail beyond 8192 (count <= CAPS-8192 = 1024, usually ~0..500)
    for (int e = lo + 16 * 512 + tid; e < hi; e += 512)
        atomicAdd(&bins[(payA[e].x >> 17) & (NPS - 1)], 1);
    __syncthreads();

    // exclusive scan over 512 bins: per-wave inclusive shfl-scan, then
    // serial scan of the 8 wave totals, then recombine.
    const int c0 = bins[tid];
    int s = c0;
    #pragma unroll
    for (int off = 1; off < 64; off <<= 1) {
        int v = __shfl_up(s, off);
        if ((tid & 63) >= off) s += v;
    }
    if ((tid & 63) == 63) wsum[tid >> 6] = s;     // wave totals
    __syncthreads();
    if (tid == 0) {
        int run = 0;
        #pragma unroll
        for (int w = 0; w < 8; ++w) { int t = wsum[w]; wsum[w] = run; run += t; }
    }
    __syncthreads();
    bcur[tid] = lo + wsum[tid >> 6] + s - c0;     // exclusive prefix
    __syncthreads();

    // CSR offsets for this super's nodes
    {
        int nd = (sp << NPSH) + tid;
        if (nd < n_nodes) offsets[nd] = bcur[tid];
    }
    __syncthreads();   // offsets reads of bcur complete before scatter mutates it

    // scatter from registers (strip dst bits -> pure src)
    #pragma unroll
    for (int j = 0; j < 16; ++j) {
        if (j < nr) {
            int q = atomicAdd(&bcur[(r[j].x >> 17) & (NPS - 1)], 1);
            sorted[q] = make_uint2(r[j].x & 0x1FFFFu, r[j].y);
        }
    }
    // tail
    for (int e = lo + 16 * 512 + tid; e < hi; e += 512) {
        uint2 p = payA[e];
        int q = atomicAdd(&bcur[(p.x >> 17) & (NPS - 1)], 1);
        sorted[q] = make_uint2(p.x & 0x1FFFFu, p.y);
    }
}

// ---------------------------------------------------------------------------
// Gather: one wave per dst node, unroll-16, plain loads (proven 102-105us;
// at the measured 2.3 TB/s random-read wall). Segment-aware end.
// ---------------------------------------------------------------------------
__global__ __launch_bounds__(256) void gather_kernel(
    const unsigned short* __restrict__ h, const int* __restrict__ offsets,
    const uint2* __restrict__ sv, const int* __restrict__ super_end,
    const float* __restrict__ bias, float* __restrict__ out, int n_nodes)
{
    int node = blockIdx.x * 4 + (threadIdx.x >> 6);
    if (node >= n_nodes) return;
    int lane = threadIdx.x & 63;
    int f = lane * 2;

    int start = offsets[node];
    int nxt   = node + 1;
    int end   = (nxt == n_nodes || (nxt & (NPS - 1)) == 0)
              ? super_end[node >> NPSH] : offsets[nxt];

    float ax = 0.f, ay = 0.f;

    for (int e = start; e < end; e += 16) {
        uint2 p[16];
        #pragma unroll
        for (int j = 0; j < 16; ++j) {
            int ei = (e + j < end) ? e + j : end - 1;
            p[j] = sv[ei];
        }
        unsigned u[16];
        #pragma unroll
        for (int j = 0; j < 16; ++j)
            u[j] = *(const unsigned*)&h[(size_t)(p[j].x & 0x00FFFFFFu) * F_OUT + f];
        #pragma unroll
        for (int j = 0; j < 16; ++j) {
            float v = (e + j < end) ? __uint_as_float(p[j].y) : 0.f;
            ax += v * __uint_as_float(u[j] << 16);
            ay += v * __uint_as_float(u[j] & 0xffff0000u);
        }
    }

    float2 b = *(const float2*)&bias[f];
    *(float2*)&out[(size_t)node * F_OUT + f] = make_float2(ax + b.x, ay + b.y);
}

// ---------------------------------------------------------------------------
extern "C" void kernel_launch(void* const* d_in, const int* in_sizes, int n_in,
                              void* d_out, int out_size, void* d_ws, size_t ws_size,
                              hipStream_t stream)
{
    const float* x     = (const float*)d_in[0];
    const int*   esrc  = (const int*)d_in[1];
    const int*   edst  = (const int*)d_in[2];
    const float* evals = (const float*)d_in[3];
    const float* W     = (const float*)d_in[4];
    const float* bias  = (const float*)d_in[5];
    float*       out   = (float*)d_out;

    const int n_nodes = in_sizes[0] / F_IN;
    const int n_edges = in_sizes[1];
    const int nsup    = (n_nodes + NPS - 1) >> NPSH;        // 196
    const int ngemm   = (n_nodes + 63) / 64;                // 1563
    const int npart   = (n_edges + BATCH - 1) / BATCH;      // 391

    auto align16 = [](size_t v) { return (v + 15) & ~(size_t)15; };
    char*  base = (char*)d_ws;
    size_t off  = 0;
    unsigned short* h  = (unsigned short*)(base + off); off = align16(off + (size_t)n_nodes * F_OUT * 2);
    unsigned short* Wt = (unsigned short*)(base + off); off = align16(off + (size_t)F_IN * F_OUT * 2);
    int*   cursorA     = (int*)(base + off);   off = align16(off + (size_t)256 * 4);
    int*   offsets     = (int*)(base + off);   off = align16(off + (size_t)n_nodes * 4);
    uint2* payA        = (uint2*)(base + off); off = align16(off + (size_t)nsup * CAPS * 8);
    uint2* sorted      = (uint2*)(base + off); off = align16(off + (size_t)nsup * CAPS * 8);
    (void)ws_size;

    // 1) Wt swizzle + cursor seed
    prep_wt_kernel<<<F_OUT, F_IN, 0, stream>>>(W, Wt, cursorA);

    // 2) fused: gemm (1563 blocks) + segmented-append partition (391 blocks)
    fused_gemm_partition_kernel<<<ngemm + npart, 256, 0, stream>>>(
        x, Wt, h, n_nodes, ngemm, esrc, edst, evals, cursorA, payA, n_edges);

    // 3) per-super sort -> CSR (single-read register-resident rewrite)
    sort_super_kernel<<<nsup, 512, 0, stream>>>(
        payA, cursorA, sorted, offsets, n_nodes);

    // 4) gather (bias fused)
    gather_kernel<<<(n_nodes + 3) / 4, 256, 0, stream>>>(
        h, offsets, sorted, cursorA, bias, out, n_nodes);
}